// Round 21
// baseline (211.528 us; speedup 1.0000x reference)
//
#include <hip/hip_runtime.h>
#include <math.h>

typedef __bf16 bf16x8 __attribute__((ext_vector_type(8)));
typedef float f32x4 __attribute__((ext_vector_type(4)));

__device__ __forceinline__ bf16x8 to_bf16x8(float4 a, float4 b) {
    bf16x8 r;
    r[0] = (__bf16)a.x; r[1] = (__bf16)a.y; r[2] = (__bf16)a.z; r[3] = (__bf16)a.w;
    r[4] = (__bf16)b.x; r[5] = (__bf16)b.y; r[6] = (__bf16)b.z; r[7] = (__bf16)b.w;
    return r;
}
#define MFMA16(A, B, C) __builtin_amdgcn_mfma_f32_16x16x32_bf16((A), (B), (C), 0, 0, 0)

// broadcast lane j (0..31) of a value DUPLICATED across both 32-lane halves
// (r9 lesson: only valid when both halves hold identical values). VALU-only.
__device__ __forceinline__ float rl(float v, int j) {
    return __int_as_float(__builtin_amdgcn_readlane(__float_as_int(v), j));
}

// sum over lanes 0..31 of a duplicated-halves value via DPP tree (VALU-only).
__device__ __forceinline__ float dpp_sum32(float v) {
    float f = v;
    f += __int_as_float(__builtin_amdgcn_update_dpp(0, __float_as_int(f), 0x111, 0xf, 0xf, true));
    f += __int_as_float(__builtin_amdgcn_update_dpp(0, __float_as_int(f), 0x112, 0xf, 0xf, true));
    f += __int_as_float(__builtin_amdgcn_update_dpp(0, __float_as_int(f), 0x114, 0xf, 0xf, true));
    f += __int_as_float(__builtin_amdgcn_update_dpp(0, __float_as_int(f), 0x118, 0xf, 0xf, true));
    f += __int_as_float(__builtin_amdgcn_update_dpp(0, __float_as_int(f), 0x142, 0xa, 0xf, false));
    return rl(f, 31);
}

#define RL_MATVEC(T, EV, OUT)                                                  \
    {                                                                          \
        float a0_ = 0.f, a1_ = 0.f, a2_ = 0.f, a3_ = 0.f;                      \
        _Pragma("unroll") for (int j_ = 0; j_ < 32; j_ += 4) {                 \
            a0_ += EV[j_ + 0] * rl((T), j_ + 0);                               \
            a1_ += EV[j_ + 1] * rl((T), j_ + 1);                               \
            a2_ += EV[j_ + 2] * rl((T), j_ + 2);                               \
            a3_ += EV[j_ + 3] * rl((T), j_ + 3);                               \
        }                                                                      \
        OUT = (a0_ + a1_) + (a2_ + a3_);                                       \
    }

// rank-1 accumulate: Scol[j] += rl(U,j) * F  (U duplicated across halves)
#define RANK1(U, F, SC)                                                        \
    {                                                                          \
        _Pragma("unroll") for (int j_ = 0; j_ < 32; j_ += 4) {                 \
            SC[j_ + 0] += rl((U), j_ + 0) * (F);                               \
            SC[j_ + 1] += rl((U), j_ + 1) * (F);                               \
            SC[j_ + 2] += rl((U), j_ + 2) * (F);                               \
            SC[j_ + 3] += rl((U), j_ + 3) * (F);                               \
        }                                                                      \
    }

// ---------------------------------------------------------------------------
// k_prep: W MFMA B-fragments in bf16, fragment-lane order (r13 mapping).
// ---------------------------------------------------------------------------
__global__ __launch_bounds__(256) void k_prep(const float* __restrict__ W,
                                              bf16x8* __restrict__ wsW) {
    const int e = blockIdx.x * 256 + threadIdx.x;   // 0..2047
    const int gk = e >> 7, h = (e >> 6) & 1, l = e & 63;
    const float* src = W + (size_t)(h * 16 + (l & 15)) * 512 + gk * 32 + (l >> 4) * 8;
    float4 lo = *(const float4*)src, hi = *(const float4*)(src + 4);
    wsW[e] = to_bf16x8(lo, hi);
}

// ---------------------------------------------------------------------------
// k_word: fused per-word pipeline, 128 threads (2 waves), 1 word/block.
// A: MFMA dots -> gd = exp(dots) into LDS (no rowmax: |dots| <= ~6.3);
//    unroll 4 => 16 loads in flight/wave (r3: full unroll spills; 4 is safe).
// C+D FUSED: alpha (w0) forward, beta (w1) backward; mid-chain barrier after
//   step 31; second half of each chain does position-D inline (r20-verified).
// ---------------------------------------------------------------------------
__global__ __launch_bounds__(128, 4) void k_word(const float* __restrict__ data,
                                                 const bf16x8* __restrict__ wsW,
                                                 const float* __restrict__ Tm,
                                                 const int* __restrict__ labels,
                                                 float* __restrict__ Pdiff,
                                                 float* __restrict__ dTpart) {
    __shared__ __align__(16) __bf16 gdb[2048];   // gd = exp(dots) (bf16)
    __shared__ __align__(16) __bf16 Unb[2048];   // alpha*gd, arbitrary scale
    __shared__ __align__(16) __bf16 Mb[2048];    // beta chain values
    __shared__ float Sb[1024];
    __shared__ float bscale[64];
    __shared__ int lab[64];

    const int n = blockIdx.x;
    const int tid = threadIdx.x;
    const int wv = tid >> 6;       // 0: alpha, 1: beta
    const int lane = tid & 63;
    const int k = tid & 31;
    float* drow = Pdiff + (size_t)n * 2048;

    // early init (issue label loads before the long A phase)
#pragma unroll
    for (int i = 0; i < 8; ++i) Sb[tid * 8 + i] = 0.f;
    if (tid < 64) { lab[tid] = labels[n * 64 + tid]; bscale[tid] = 1.f; }

    // ---- Phase A: MFMA dots -> gd = exp(dots) into LDS ----
    {
        const int m16 = lane & 15;
        const int kb = lane >> 4;
        const size_t row0 = (size_t)n * 64 + wv * 32;
        const float* arow0 = data + (row0 + m16) * 512 + kb * 8;
        const float* arow1 = arow0 + 16 * 512;

        f32x4 acc00 = {0.f, 0.f, 0.f, 0.f}, acc01 = {0.f, 0.f, 0.f, 0.f};
        f32x4 acc10 = {0.f, 0.f, 0.f, 0.f}, acc11 = {0.f, 0.f, 0.f, 0.f};

#pragma unroll 4   // 16 loads in flight; full unroll spills (r3)
        for (int kk = 0; kk < 16; ++kk) {
            const int off = kk * 32;
            float4 a0l = *(const float4*)(arow0 + off);
            float4 a0h = *(const float4*)(arow0 + off + 4);
            float4 a1l = *(const float4*)(arow1 + off);
            float4 a1h = *(const float4*)(arow1 + off + 4);
            bf16x8 a0 = to_bf16x8(a0l, a0h), a1 = to_bf16x8(a1l, a1h);
            bf16x8 b0 = wsW[kk * 128 + lane];
            bf16x8 b1 = wsW[kk * 128 + 64 + lane];
            acc00 = MFMA16(a0, b0, acc00);
            acc01 = MFMA16(a0, b1, acc01);
            acc10 = MFMA16(a1, b0, acc10);
            acc11 = MFMA16(a1, b1, acc11);
        }
        const int ib = wv * 32 + kb * 4;
#pragma unroll
        for (int r = 0; r < 4; ++r) {
            gdb[(ib + r) * 32 + m16]           = (__bf16)__expf(acc00[r]);
            gdb[(ib + r) * 32 + 16 + m16]      = (__bf16)__expf(acc01[r]);
            gdb[(ib + 16 + r) * 32 + m16]      = (__bf16)__expf(acc10[r]);
            gdb[(ib + 16 + r) * 32 + 16 + m16] = (__bf16)__expf(acc11[r]);
        }
    }
    __syncthreads();

    float Scol[32];
#pragma unroll
    for (int j = 0; j < 32; ++j) Scol[j] = 0.f;

    if (wv == 0) {
        // ================= ALPHA =================
        float Ecol[32];
#pragma unroll
        for (int j = 0; j < 32; ++j) Ecol[j] = __expf(Tm[j * 32 + k]);
        float Areg = 1.f;
        float gdc = (float)gdb[k];
        // --- first half: steps 0..31, pure chain ---
#pragma unroll 1
        for (int g = 0; g < 8; ++g) {
#pragma unroll
            for (int ii = 0; ii < 4; ++ii) {
                const int i = g * 4 + ii;
                float t = Areg * gdc;
                Unb[i * 32 + k] = (__bf16)t;
                gdc = (float)gdb[(i + 1) * 32 + k];
                float anew;
                RL_MATVEC(t, Ecol, anew);
                Areg = anew;
            }
            Areg *= __builtin_amdgcn_rcpf(rl(Areg, 0));
        }
        __syncthreads();   // mid-chain crossover barrier
        // --- second half: steps 32..63, chain + inline D for position i ---
#pragma unroll 1
        for (int g = 8; g < 16; ++g) {
#pragma unroll
            for (int ii = 0; ii < 4; ++ii) {
                const int i = g * 4 + ii;
                float t = Areg * gdc;
                Unb[i * 32 + k] = (__bf16)t;
                float mm = (float)Mb[i * 32 + k];
                float gdn = 0.f, mbn = 0.f;
                if (i < 63) {
                    gdn = (float)gdb[(i + 1) * 32 + k];
                    mbn = (float)Mb[(i + 1) * 32 + k];
                }
                float Z = dpp_sum32(t * mm);
                float rZ = __builtin_amdgcn_rcpf(Z);
                float pd = ((lab[i] == k) ? 1.f : 0.f) - t * mm * rZ;
                if (lane < 32) drow[i * 32 + k] = pd;
                if (i < 63) {
                    float f = gdn * mbn * rZ * bscale[i];   // bscale: beta pre-barrier
                    RANK1(t, f, Scol);
                    float anew;
                    RL_MATVEC(t, Ecol, anew);
                    Areg = anew;
                    gdc = gdn;
                }
            }
            if (g < 15) Areg *= __builtin_amdgcn_rcpf(rl(Areg, 0));
        }
    } else {
        // ================= BETA =================
        float Erow[32];
#pragma unroll
        for (int j = 0; j < 32; ++j) Erow[j] = __expf(Tm[k * 32 + j]);
        float Mreg = 1.f;
        Mb[63 * 32 + k] = (__bf16)1.f;
        float gdc = (float)gdb[63 * 32 + k];
        float mst = 1.f;   // raw stored value of the most recent Mb write
        // --- first half: s=0..31, writes Mb[62..31], pure chain ---
#pragma unroll 1
        for (int g = 0; g < 8; ++g) {
#pragma unroll
            for (int ii = 0; ii < 4; ++ii) {
                const int s = g * 4 + ii;
                const int i = 63 - s;
                float ww = gdc * Mreg;
                gdc = (float)gdb[(i - 1) * 32 + k];
                float m2;
                RL_MATVEC(ww, Erow, m2);
                Mb[(i - 1) * 32 + k] = (__bf16)m2;
                Mreg = m2;
                mst = m2;
            }
            {
                float rc = __builtin_amdgcn_rcpf(rl(Mreg, 0));
                Mreg *= rc;
                if (lane == 0) bscale[58 - 4 * g] = rc;   // g=7 -> bscale[30]
            }
        }
        __syncthreads();   // mid-chain crossover barrier
        // --- D for position 31 (Mb[31]=mst raw; Mb[32],Un[31] from LDS) ---
        {
            float un = (float)Unb[31 * 32 + k];
            float mbn = (float)Mb[32 * 32 + k];
            float gdn = (float)gdb[32 * 32 + k];
            float Z = dpp_sum32(un * mst);
            float rZ = __builtin_amdgcn_rcpf(Z);
            float pd = ((lab[31] == k) ? 1.f : 0.f) - un * mst * rZ;
            if (lane < 32) drow[31 * 32 + k] = pd;
            float f = gdn * mbn * rZ;   // bscale[31] == 1
            RANK1(un, f, Scol);
        }
        // --- second half: s=32..62, writes Mb[30..0], D for p=i-1=30..0 ---
#pragma unroll 1
        for (int g = 8; g < 16; ++g) {
#pragma unroll
            for (int ii = 0; ii < 4; ++ii) {
                const int s = g * 4 + ii;
                if (s < 63) {
                    const int i = 63 - s;        // 31..1
                    const int p = i - 1;         // 30..0
                    float gd_i = gdc;            // = gd[i] = gd[p+1]
                    float ww = gd_i * Mreg;
                    gdc = (float)gdb[p * 32 + k];
                    float m2;
                    RL_MATVEC(ww, Erow, m2);
                    Mb[p * 32 + k] = (__bf16)m2;
                    // D for position p: mm = m2 (raw), Mb[p+1]_stored = mst
                    float un = (float)Unb[p * 32 + k];   // alpha pre-barrier
                    float Z = dpp_sum32(un * m2);
                    float rZ = __builtin_amdgcn_rcpf(Z);
                    float pd = ((lab[p] == k) ? 1.f : 0.f) - un * m2 * rZ;
                    if (lane < 32) drow[p * 32 + k] = pd;
                    float f = gd_i * mst * rZ * bscale[p];
                    RANK1(un, f, Scol);
                    Mreg = m2;
                    mst = m2;
                }
            }
            if (g < 15) {
                float rc = __builtin_amdgcn_rcpf(rl(Mreg, 0));
                Mreg *= rc;
                if (lane == 0) bscale[58 - 4 * g] = rc;
            }
        }
    }
    // Sb accumulation (Scol duplicated across halves: lane<32 contributes)
    if (lane < 32) {
#pragma unroll
        for (int j = 0; j < 32; ++j) atomicAdd(&Sb[j * 32 + k], Scol[j]);
    }
    __syncthreads();

    // dT row: plain stores initialize the whole row, then hist atomics on top.
    float* op = dTpart + (size_t)n * 1024;
#pragma unroll
    for (int e = 0; e < 8; ++e) {
        const int idx = tid * 8 + e;
        op[idx] = -__expf(Tm[idx]) * Sb[idx];
    }
    __syncthreads();
    if (tid < 63) atomicAdd(&op[lab[tid] * 32 + lab[tid + 1]], 1.0f);
}

// ---------------------------------------------------------------------------
// K3: dw partials = Pdiff^T @ data. grid = 256 word-groups x 4 d-quarters.
// (~48 us, near the fp32 stream floor.)
// ---------------------------------------------------------------------------
__global__ __launch_bounds__(256) void k_dw(const float* __restrict__ data,
                                            const float* __restrict__ Pd,
                                            float* __restrict__ dwp) {
    const int g = blockIdx.x >> 2;
    const int q = blockIdx.x & 3;
    const int tid = threadIdx.x;
    const int kg = __builtin_amdgcn_readfirstlane(tid >> 6);
    const int lane = tid & 63;
    const int k0 = kg << 3;
    const int d0 = q * 128 + lane * 2;

    float2 acc[8];
#pragma unroll
    for (int i = 0; i < 8; ++i) acc[i] = make_float2(0.f, 0.f);

    const size_t rbase = (size_t)g * 512;
    const float* dptr = data + rbase * 512 + d0;
    const float4* pptr = (const float4*)(Pd + rbase * 32) + kg * 2;

#define FMA8_2(PA, PB, DV)                                                     \
    acc[0].x += (PA).x * (DV).x; acc[0].y += (PA).x * (DV).y;                  \
    acc[1].x += (PA).y * (DV).x; acc[1].y += (PA).y * (DV).y;                  \
    acc[2].x += (PA).z * (DV).x; acc[2].y += (PA).z * (DV).y;                  \
    acc[3].x += (PA).w * (DV).x; acc[3].y += (PA).w * (DV).y;                  \
    acc[4].x += (PB).x * (DV).x; acc[4].y += (PB).x * (DV).y;                  \
    acc[5].x += (PB).y * (DV).x; acc[5].y += (PB).y * (DV).y;                  \
    acc[6].x += (PB).z * (DV).x; acc[6].y += (PB).z * (DV).y;                  \
    acc[7].x += (PB).w * (DV).x; acc[7].y += (PB).w * (DV).y;

    for (int r = 0; r < 512; r += 4) {
        float2 dv0 = *(const float2*)(dptr + (size_t)(r + 0) * 512);
        float2 dv1 = *(const float2*)(dptr + (size_t)(r + 1) * 512);
        float2 dv2 = *(const float2*)(dptr + (size_t)(r + 2) * 512);
        float2 dv3 = *(const float2*)(dptr + (size_t)(r + 3) * 512);
        float4 pa0 = pptr[(r + 0) * 8], pb0 = pptr[(r + 0) * 8 + 1];
        float4 pa1 = pptr[(r + 1) * 8], pb1 = pptr[(r + 1) * 8 + 1];
        float4 pa2 = pptr[(r + 2) * 8], pb2 = pptr[(r + 2) * 8 + 1];
        float4 pa3 = pptr[(r + 3) * 8], pb3 = pptr[(r + 3) * 8 + 1];
        FMA8_2(pa0, pb0, dv0)
        FMA8_2(pa1, pb1, dv1)
        FMA8_2(pa2, pb2, dv2)
        FMA8_2(pa3, pb3, dv3)
    }
#undef FMA8_2

    float* op = dwp + (size_t)g * 16384;
#pragma unroll
    for (int kk = 0; kk < 8; ++kk)
        *(float2*)(op + (k0 + kk) * 512 + d0) = acc[kk];
}

// ---------------------------------------------------------------------------
// K4: reduce partials, scale 1/N. blocks 0..255: dw; 256..319: dT.
// ---------------------------------------------------------------------------
__global__ __launch_bounds__(256) void k_final(const float* __restrict__ dwp,
                                               const float* __restrict__ dTp,
                                               float* __restrict__ out) {
    __shared__ float red[256];
    const int b = blockIdx.x, t = threadIdx.x;
    const float inv = 1.0f / 2048.0f;
    if (b < 256) {
        const int q = t >> 6, ol = t & 63;
        const int oi = b * 64 + ol;
        float s = 0.f;
#pragma unroll 4
        for (int j = 0; j < 64; ++j) s += dwp[(size_t)(q * 64 + j) * 16384 + oi];
        red[t] = s;
        __syncthreads();
        if (t < 64) out[b * 64 + t] = (red[t] + red[t + 64] + red[t + 128] + red[t + 192]) * inv;
    } else {
        const int ol = t >> 4, q = t & 15;
        const int oi = (b - 256) * 16 + ol;
        float s = 0.f;
#pragma unroll 4
        for (int j = 0; j < 128; ++j) s += dTp[(size_t)(q * 128 + j) * 1024 + oi];
        s += __shfl_xor(s, 1, 16); s += __shfl_xor(s, 2, 16);
        s += __shfl_xor(s, 4, 16); s += __shfl_xor(s, 8, 16);
        if (q == 0) out[16384 + oi] = s * inv;
    }
}

// ---------------------------------------------------------------------------
// ws layout (floats): [0,4194304) Pdiff | [4194304,6291456) dT partials
//                     [6291456,10485760) dw partials | [10485760,+8192) wsW
// ---------------------------------------------------------------------------
extern "C" void kernel_launch(void* const* d_in, const int* in_sizes, int n_in,
                              void* d_out, int out_size, void* d_ws, size_t ws_size,
                              hipStream_t stream) {
    const float* W = (const float*)d_in[0];
    const float* Tm = (const float*)d_in[1];
    const float* data = (const float*)d_in[2];
    const int* labels = (const int*)d_in[3];
    float* out = (float*)d_out;
    float* ws = (float*)d_ws;

    float* Pdiff = ws;                        // 2048*64*32
    float* dTpart = ws + 4194304;             // 2048*1024
    float* dwpart = ws + 6291456;             // 256*16384
    bf16x8* wsW = (bf16x8*)(ws + 10485760);   // 2048 frags * 16 B

    hipLaunchKernelGGL(k_prep, dim3(8), dim3(256), 0, stream, W, wsW);
    hipLaunchKernelGGL(k_word, dim3(2048), dim3(128), 0, stream,
                       data, wsW, Tm, labels, Pdiff, dTpart);
    hipLaunchKernelGGL(k_dw, dim3(1024), dim3(256), 0, stream, data, Pdiff, dwpart);
    hipLaunchKernelGGL(k_final, dim3(320), dim3(256), 0, stream, dwpart, dTpart, out);
}

// Round 22
// 207.397 us; speedup vs baseline: 1.0199x; 1.0199x over previous
//
#include <hip/hip_runtime.h>
#include <math.h>

typedef __bf16 bf16x8 __attribute__((ext_vector_type(8)));
typedef float f32x4 __attribute__((ext_vector_type(4)));

__device__ __forceinline__ bf16x8 to_bf16x8(float4 a, float4 b) {
    bf16x8 r;
    r[0] = (__bf16)a.x; r[1] = (__bf16)a.y; r[2] = (__bf16)a.z; r[3] = (__bf16)a.w;
    r[4] = (__bf16)b.x; r[5] = (__bf16)b.y; r[6] = (__bf16)b.z; r[7] = (__bf16)b.w;
    return r;
}
#define MFMA16(A, B, C) __builtin_amdgcn_mfma_f32_16x16x32_bf16((A), (B), (C), 0, 0, 0)

// broadcast lane j (0..31) of a value DUPLICATED across both 32-lane halves
// (r9 lesson: only valid when both halves hold identical values). VALU-only.
__device__ __forceinline__ float rl(float v, int j) {
    return __int_as_float(__builtin_amdgcn_readlane(__float_as_int(v), j));
}

// sum over lanes 0..31 of a duplicated-halves value via DPP tree (VALU-only).
__device__ __forceinline__ float dpp_sum32(float v) {
    float f = v;
    f += __int_as_float(__builtin_amdgcn_update_dpp(0, __float_as_int(f), 0x111, 0xf, 0xf, true));
    f += __int_as_float(__builtin_amdgcn_update_dpp(0, __float_as_int(f), 0x112, 0xf, 0xf, true));
    f += __int_as_float(__builtin_amdgcn_update_dpp(0, __float_as_int(f), 0x114, 0xf, 0xf, true));
    f += __int_as_float(__builtin_amdgcn_update_dpp(0, __float_as_int(f), 0x118, 0xf, 0xf, true));
    f += __int_as_float(__builtin_amdgcn_update_dpp(0, __float_as_int(f), 0x142, 0xa, 0xf, false));
    return rl(f, 31);
}

#define RL_MATVEC(T, EV, OUT)                                                  \
    {                                                                          \
        float a0_ = 0.f, a1_ = 0.f, a2_ = 0.f, a3_ = 0.f;                      \
        _Pragma("unroll") for (int j_ = 0; j_ < 32; j_ += 4) {                 \
            a0_ += EV[j_ + 0] * rl((T), j_ + 0);                               \
            a1_ += EV[j_ + 1] * rl((T), j_ + 1);                               \
            a2_ += EV[j_ + 2] * rl((T), j_ + 2);                               \
            a3_ += EV[j_ + 3] * rl((T), j_ + 3);                               \
        }                                                                      \
        OUT = (a0_ + a1_) + (a2_ + a3_);                                       \
    }

// rank-1 accumulate: Scol[j] += rl(U,j) * F  (U duplicated across halves)
#define RANK1(U, F, SC)                                                        \
    {                                                                          \
        _Pragma("unroll") for (int j_ = 0; j_ < 32; j_ += 4) {                 \
            SC[j_ + 0] += rl((U), j_ + 0) * (F);                               \
            SC[j_ + 1] += rl((U), j_ + 1) * (F);                               \
            SC[j_ + 2] += rl((U), j_ + 2) * (F);                               \
            SC[j_ + 3] += rl((U), j_ + 3) * (F);                               \
        }                                                                      \
    }

// ---------------------------------------------------------------------------
// k_prep: W MFMA B-fragments in bf16, fragment-lane order (r13 mapping).
// ---------------------------------------------------------------------------
__global__ __launch_bounds__(256) void k_prep(const float* __restrict__ W,
                                              bf16x8* __restrict__ wsW) {
    const int e = blockIdx.x * 256 + threadIdx.x;   // 0..2047
    const int gk = e >> 7, h = (e >> 6) & 1, l = e & 63;
    const float* src = W + (size_t)(h * 16 + (l & 15)) * 512 + gk * 32 + (l >> 4) * 8;
    float4 lo = *(const float4*)src, hi = *(const float4*)(src + 4);
    wsW[e] = to_bf16x8(lo, hi);
}

// ---------------------------------------------------------------------------
// k_word: fused per-word pipeline, 128 threads (2 waves), 1 word/block.
// A: MFMA dots -> gd = exp(dots) into LDS (no rowmax: |dots| <= ~6.3).
// C+D FUSED: alpha (w0) forward, beta (w1) backward; mid-chain barrier after
//   step 31. Second half of each chain performs position-D inline:
//   alpha does D for i=32..63 (Un in reg; Mb[i],Mb[i+1],bscale[>=34] from
//   beta's pre-barrier writes); beta does D for p=31..0 (Mb in reg via mst;
//   Un[0..31] from alpha's pre-barrier writes; bscale[p] written one group
//   ahead of use). Z via dpp_sum32; rank-1 via readlane; single-lane renorm.
// (r20-verified best configuration: unroll 2, init after phase A.)
// ---------------------------------------------------------------------------
__global__ __launch_bounds__(128) void k_word(const float* __restrict__ data,
                                              const bf16x8* __restrict__ wsW,
                                              const float* __restrict__ Tm,
                                              const int* __restrict__ labels,
                                              float* __restrict__ Pdiff,
                                              float* __restrict__ dTpart) {
    __shared__ __align__(16) __bf16 gdb[2048];   // gd = exp(dots) (bf16)
    __shared__ __align__(16) __bf16 Unb[2048];   // alpha*gd, arbitrary scale
    __shared__ __align__(16) __bf16 Mb[2048];    // beta chain values
    __shared__ float Sb[1024];
    __shared__ float bscale[64];
    __shared__ int lab[64];

    const int n = blockIdx.x;
    const int tid = threadIdx.x;
    const int wv = tid >> 6;       // 0: alpha, 1: beta
    const int lane = tid & 63;
    const int k = tid & 31;
    float* drow = Pdiff + (size_t)n * 2048;

    // ---- Phase A: MFMA dots -> gd = exp(dots) into LDS ----
    {
        const int m16 = lane & 15;
        const int kb = lane >> 4;
        const size_t row0 = (size_t)n * 64 + wv * 32;
        const float* arow0 = data + (row0 + m16) * 512 + kb * 8;
        const float* arow1 = arow0 + 16 * 512;

        f32x4 acc00 = {0.f, 0.f, 0.f, 0.f}, acc01 = {0.f, 0.f, 0.f, 0.f};
        f32x4 acc10 = {0.f, 0.f, 0.f, 0.f}, acc11 = {0.f, 0.f, 0.f, 0.f};

#pragma unroll 2   // 2-deep: loads in flight; full unroll spills (r3)
        for (int kk = 0; kk < 16; ++kk) {
            const int off = kk * 32;
            float4 a0l = *(const float4*)(arow0 + off);
            float4 a0h = *(const float4*)(arow0 + off + 4);
            float4 a1l = *(const float4*)(arow1 + off);
            float4 a1h = *(const float4*)(arow1 + off + 4);
            bf16x8 a0 = to_bf16x8(a0l, a0h), a1 = to_bf16x8(a1l, a1h);
            bf16x8 b0 = wsW[kk * 128 + lane];
            bf16x8 b1 = wsW[kk * 128 + 64 + lane];
            acc00 = MFMA16(a0, b0, acc00);
            acc01 = MFMA16(a0, b1, acc01);
            acc10 = MFMA16(a1, b0, acc10);
            acc11 = MFMA16(a1, b1, acc11);
        }
        const int ib = wv * 32 + kb * 4;
#pragma unroll
        for (int r = 0; r < 4; ++r) {
            gdb[(ib + r) * 32 + m16]           = (__bf16)__expf(acc00[r]);
            gdb[(ib + r) * 32 + 16 + m16]      = (__bf16)__expf(acc01[r]);
            gdb[(ib + 16 + r) * 32 + m16]      = (__bf16)__expf(acc10[r]);
            gdb[(ib + 16 + r) * 32 + 16 + m16] = (__bf16)__expf(acc11[r]);
        }
    }
#pragma unroll
    for (int i = 0; i < 8; ++i) Sb[tid * 8 + i] = 0.f;
    if (tid < 64) { lab[tid] = labels[n * 64 + tid]; bscale[tid] = 1.f; }
    __syncthreads();

    float Scol[32];
#pragma unroll
    for (int j = 0; j < 32; ++j) Scol[j] = 0.f;

    if (wv == 0) {
        // ================= ALPHA =================
        float Ecol[32];
#pragma unroll
        for (int j = 0; j < 32; ++j) Ecol[j] = __expf(Tm[j * 32 + k]);
        float Areg = 1.f;
        float gdc = (float)gdb[k];
        // --- first half: steps 0..31, pure chain ---
#pragma unroll 1
        for (int g = 0; g < 8; ++g) {
#pragma unroll
            for (int ii = 0; ii < 4; ++ii) {
                const int i = g * 4 + ii;
                float t = Areg * gdc;
                Unb[i * 32 + k] = (__bf16)t;
                gdc = (float)gdb[(i + 1) * 32 + k];
                float anew;
                RL_MATVEC(t, Ecol, anew);
                Areg = anew;
            }
            Areg *= __builtin_amdgcn_rcpf(rl(Areg, 0));
        }
        __syncthreads();   // mid-chain crossover barrier
        // --- second half: steps 32..63, chain + inline D for position i ---
#pragma unroll 1
        for (int g = 8; g < 16; ++g) {
#pragma unroll
            for (int ii = 0; ii < 4; ++ii) {
                const int i = g * 4 + ii;
                float t = Areg * gdc;
                Unb[i * 32 + k] = (__bf16)t;
                float mm = (float)Mb[i * 32 + k];
                float gdn = 0.f, mbn = 0.f;
                if (i < 63) {
                    gdn = (float)gdb[(i + 1) * 32 + k];
                    mbn = (float)Mb[(i + 1) * 32 + k];
                }
                float Z = dpp_sum32(t * mm);
                float rZ = __builtin_amdgcn_rcpf(Z);
                float pd = ((lab[i] == k) ? 1.f : 0.f) - t * mm * rZ;
                if (lane < 32) drow[i * 32 + k] = pd;
                if (i < 63) {
                    float f = gdn * mbn * rZ * bscale[i];   // bscale: beta pre-barrier
                    RANK1(t, f, Scol);
                    float anew;
                    RL_MATVEC(t, Ecol, anew);
                    Areg = anew;
                    gdc = gdn;
                }
            }
            if (g < 15) Areg *= __builtin_amdgcn_rcpf(rl(Areg, 0));
        }
    } else {
        // ================= BETA =================
        float Erow[32];
#pragma unroll
        for (int j = 0; j < 32; ++j) Erow[j] = __expf(Tm[k * 32 + j]);
        float Mreg = 1.f;
        Mb[63 * 32 + k] = (__bf16)1.f;
        float gdc = (float)gdb[63 * 32 + k];
        float mst = 1.f;   // raw stored value of the most recent Mb write
        // --- first half: s=0..31, writes Mb[62..31], pure chain ---
#pragma unroll 1
        for (int g = 0; g < 8; ++g) {
#pragma unroll
            for (int ii = 0; ii < 4; ++ii) {
                const int s = g * 4 + ii;
                const int i = 63 - s;
                float ww = gdc * Mreg;
                gdc = (float)gdb[(i - 1) * 32 + k];
                float m2;
                RL_MATVEC(ww, Erow, m2);
                Mb[(i - 1) * 32 + k] = (__bf16)m2;
                Mreg = m2;
                mst = m2;
            }
            {
                float rc = __builtin_amdgcn_rcpf(rl(Mreg, 0));
                Mreg *= rc;
                if (lane == 0) bscale[58 - 4 * g] = rc;   // g=7 -> bscale[30]
            }
        }
        __syncthreads();   // mid-chain crossover barrier
        // --- D for position 31 (Mb[31]=mst raw; Mb[32],Un[31] from LDS) ---
        {
            float un = (float)Unb[31 * 32 + k];
            float mbn = (float)Mb[32 * 32 + k];
            float gdn = (float)gdb[32 * 32 + k];
            float Z = dpp_sum32(un * mst);
            float rZ = __builtin_amdgcn_rcpf(Z);
            float pd = ((lab[31] == k) ? 1.f : 0.f) - un * mst * rZ;
            if (lane < 32) drow[31 * 32 + k] = pd;
            float f = gdn * mbn * rZ;   // bscale[31] == 1
            RANK1(un, f, Scol);
        }
        // --- second half: s=32..62, writes Mb[30..0], D for p=i-1=30..0 ---
#pragma unroll 1
        for (int g = 8; g < 16; ++g) {
#pragma unroll
            for (int ii = 0; ii < 4; ++ii) {
                const int s = g * 4 + ii;
                if (s < 63) {
                    const int i = 63 - s;        // 31..1
                    const int p = i - 1;         // 30..0
                    float gd_i = gdc;            // = gd[i] = gd[p+1]
                    float ww = gd_i * Mreg;
                    gdc = (float)gdb[p * 32 + k];
                    float m2;
                    RL_MATVEC(ww, Erow, m2);
                    Mb[p * 32 + k] = (__bf16)m2;
                    // D for position p: mm = m2 (raw), Mb[p+1]_stored = mst
                    float un = (float)Unb[p * 32 + k];   // alpha pre-barrier
                    float Z = dpp_sum32(un * m2);
                    float rZ = __builtin_amdgcn_rcpf(Z);
                    float pd = ((lab[p] == k) ? 1.f : 0.f) - un * m2 * rZ;
                    if (lane < 32) drow[p * 32 + k] = pd;
                    float f = gd_i * mst * rZ * bscale[p];
                    RANK1(un, f, Scol);
                    Mreg = m2;
                    mst = m2;
                }
            }
            if (g < 15) {
                float rc = __builtin_amdgcn_rcpf(rl(Mreg, 0));
                Mreg *= rc;
                if (lane == 0) bscale[58 - 4 * g] = rc;
            }
        }
    }
    // Sb accumulation (Scol duplicated across halves: lane<32 contributes)
    if (lane < 32) {
#pragma unroll
        for (int j = 0; j < 32; ++j) atomicAdd(&Sb[j * 32 + k], Scol[j]);
    }
    __syncthreads();

    // dT row: plain stores initialize the whole row, then hist atomics on top.
    float* op = dTpart + (size_t)n * 1024;
#pragma unroll
    for (int e = 0; e < 8; ++e) {
        const int idx = tid * 8 + e;
        op[idx] = -__expf(Tm[idx]) * Sb[idx];
    }
    __syncthreads();
    if (tid < 63) atomicAdd(&op[lab[tid] * 32 + lab[tid + 1]], 1.0f);
}

// ---------------------------------------------------------------------------
// K3: dw partials = Pdiff^T @ data. grid = 256 word-groups x 4 d-quarters.
// (~48 us, near the fp32 stream floor.)
// ---------------------------------------------------------------------------
__global__ __launch_bounds__(256) void k_dw(const float* __restrict__ data,
                                            const float* __restrict__ Pd,
                                            float* __restrict__ dwp) {
    const int g = blockIdx.x >> 2;
    const int q = blockIdx.x & 3;
    const int tid = threadIdx.x;
    const int kg = __builtin_amdgcn_readfirstlane(tid >> 6);
    const int lane = tid & 63;
    const int k0 = kg << 3;
    const int d0 = q * 128 + lane * 2;

    float2 acc[8];
#pragma unroll
    for (int i = 0; i < 8; ++i) acc[i] = make_float2(0.f, 0.f);

    const size_t rbase = (size_t)g * 512;
    const float* dptr = data + rbase * 512 + d0;
    const float4* pptr = (const float4*)(Pd + rbase * 32) + kg * 2;

#define FMA8_2(PA, PB, DV)                                                     \
    acc[0].x += (PA).x * (DV).x; acc[0].y += (PA).x * (DV).y;                  \
    acc[1].x += (PA).y * (DV).x; acc[1].y += (PA).y * (DV).y;                  \
    acc[2].x += (PA).z * (DV).x; acc[2].y += (PA).z * (DV).y;                  \
    acc[3].x += (PA).w * (DV).x; acc[3].y += (PA).w * (DV).y;                  \
    acc[4].x += (PB).x * (DV).x; acc[4].y += (PB).x * (DV).y;                  \
    acc[5].x += (PB).y * (DV).x; acc[5].y += (PB).y * (DV).y;                  \
    acc[6].x += (PB).z * (DV).x; acc[6].y += (PB).z * (DV).y;                  \
    acc[7].x += (PB).w * (DV).x; acc[7].y += (PB).w * (DV).y;

    for (int r = 0; r < 512; r += 4) {
        float2 dv0 = *(const float2*)(dptr + (size_t)(r + 0) * 512);
        float2 dv1 = *(const float2*)(dptr + (size_t)(r + 1) * 512);
        float2 dv2 = *(const float2*)(dptr + (size_t)(r + 2) * 512);
        float2 dv3 = *(const float2*)(dptr + (size_t)(r + 3) * 512);
        float4 pa0 = pptr[(r + 0) * 8], pb0 = pptr[(r + 0) * 8 + 1];
        float4 pa1 = pptr[(r + 1) * 8], pb1 = pptr[(r + 1) * 8 + 1];
        float4 pa2 = pptr[(r + 2) * 8], pb2 = pptr[(r + 2) * 8 + 1];
        float4 pa3 = pptr[(r + 3) * 8], pb3 = pptr[(r + 3) * 8 + 1];
        FMA8_2(pa0, pb0, dv0)
        FMA8_2(pa1, pb1, dv1)
        FMA8_2(pa2, pb2, dv2)
        FMA8_2(pa3, pb3, dv3)
    }
#undef FMA8_2

    float* op = dwp + (size_t)g * 16384;
#pragma unroll
    for (int kk = 0; kk < 8; ++kk)
        *(float2*)(op + (k0 + kk) * 512 + d0) = acc[kk];
}

// ---------------------------------------------------------------------------
// K4: reduce partials, scale 1/N. blocks 0..255: dw; 256..319: dT.
// ---------------------------------------------------------------------------
__global__ __launch_bounds__(256) void k_final(const float* __restrict__ dwp,
                                               const float* __restrict__ dTp,
                                               float* __restrict__ out) {
    __shared__ float red[256];
    const int b = blockIdx.x, t = threadIdx.x;
    const float inv = 1.0f / 2048.0f;
    if (b < 256) {
        const int q = t >> 6, ol = t & 63;
        const int oi = b * 64 + ol;
        float s = 0.f;
#pragma unroll 4
        for (int j = 0; j < 64; ++j) s += dwp[(size_t)(q * 64 + j) * 16384 + oi];
        red[t] = s;
        __syncthreads();
        if (t < 64) out[b * 64 + t] = (red[t] + red[t + 64] + red[t + 128] + red[t + 192]) * inv;
    } else {
        const int ol = t >> 4, q = t & 15;
        const int oi = (b - 256) * 16 + ol;
        float s = 0.f;
#pragma unroll 4
        for (int j = 0; j < 128; ++j) s += dTp[(size_t)(q * 128 + j) * 1024 + oi];
        s += __shfl_xor(s, 1, 16); s += __shfl_xor(s, 2, 16);
        s += __shfl_xor(s, 4, 16); s += __shfl_xor(s, 8, 16);
        if (q == 0) out[16384 + oi] = s * inv;
    }
}

// ---------------------------------------------------------------------------
// ws layout (floats): [0,4194304) Pdiff | [4194304,6291456) dT partials
//                     [6291456,10485760) dw partials | [10485760,+8192) wsW
// ---------------------------------------------------------------------------
extern "C" void kernel_launch(void* const* d_in, const int* in_sizes, int n_in,
                              void* d_out, int out_size, void* d_ws, size_t ws_size,
                              hipStream_t stream) {
    const float* W = (const float*)d_in[0];
    const float* Tm = (const float*)d_in[1];
    const float* data = (const float*)d_in[2];
    const int* labels = (const int*)d_in[3];
    float* out = (float*)d_out;
    float* ws = (float*)d_ws;

    float* Pdiff = ws;                        // 2048*64*32
    float* dTpart = ws + 4194304;             // 2048*1024
    float* dwpart = ws + 6291456;             // 256*16384
    bf16x8* wsW = (bf16x8*)(ws + 10485760);   // 2048 frags * 16 B

    hipLaunchKernelGGL(k_prep, dim3(8), dim3(256), 0, stream, W, wsW);
    hipLaunchKernelGGL(k_word, dim3(2048), dim3(128), 0, stream,
                       data, wsW, Tm, labels, Pdiff, dTpart);
    hipLaunchKernelGGL(k_dw, dim3(1024), dim3(256), 0, stream, data, Pdiff, dwpart);
    hipLaunchKernelGGL(k_final, dim3(320), dim3(256), 0, stream, dwpart, dTpart, out);
}